// Round 1
// baseline (74.898 us; speedup 1.0000x reference)
//
#include <hip/hip_runtime.h>

#define N 1024
#define D 128
#define PAD 132   // 128 + 4: keeps rows 16B-aligned (528 B), bank stride 132%32=4

// ---------------------------------------------------------------------------
// Phase A: S[i][j] = relu( sum_d |x[i][d]-x[j][d]| * w[d] + bias )
// 64x64 tile per block, 256 threads, 4x4 micro-tile (lane-strided mapping).
// ---------------------------------------------------------------------------
__global__ __launch_bounds__(256) void scores_kernel(
    const float* __restrict__ x, const float* __restrict__ w,
    const float* __restrict__ bias, float* __restrict__ S) {
  __shared__ float sxi[64 * PAD];
  __shared__ float sxj[64 * PAD];
  __shared__ float sw[D];

  const int t  = threadIdx.x;
  const int bi = blockIdx.y * 64;
  const int bj = blockIdx.x * 64;

  // ---- stage both tiles (coalesced float4 global reads), one barrier ----
  {
    const int c  = t & 31;   // float4 index within a 128-float row
    const int r0 = t >> 5;   // 0..7, 8 rows per pass
    #pragma unroll
    for (int p = 0; p < 8; ++p) {
      const int r = r0 + p * 8;
      const float4 vi = reinterpret_cast<const float4*>(x)[(bi + r) * 32 + c];
      const float4 vj = reinterpret_cast<const float4*>(x)[(bj + r) * 32 + c];
      *reinterpret_cast<float4*>(&sxi[r * PAD + c * 4]) = vi;
      *reinterpret_cast<float4*>(&sxj[r * PAD + c * 4]) = vj;
    }
    if (t < 32) {
      reinterpret_cast<float4*>(sw)[t] = reinterpret_cast<const float4*>(w)[t];
    }
  }
  __syncthreads();

  const int tx = t & 15;   // col group: cols tx + 16*b
  const int ty = t >> 4;   // row group: rows ty + 16*a

  float acc[4][4];
  #pragma unroll
  for (int a = 0; a < 4; ++a)
    #pragma unroll
    for (int b = 0; b < 4; ++b) acc[a][b] = 0.f;

  #pragma unroll 4
  for (int d = 0; d < D; d += 4) {
    float4 A[4], B[4];
    #pragma unroll
    for (int a = 0; a < 4; ++a)
      A[a] = *reinterpret_cast<const float4*>(&sxi[(ty + 16 * a) * PAD + d]);
    #pragma unroll
    for (int b = 0; b < 4; ++b)
      B[b] = *reinterpret_cast<const float4*>(&sxj[(tx + 16 * b) * PAD + d]);
    const float4 W = *reinterpret_cast<const float4*>(&sw[d]);

    #pragma unroll
    for (int a = 0; a < 4; ++a) {
      #pragma unroll
      for (int b = 0; b < 4; ++b) {
        float s = acc[a][b];
        s = fmaf(fabsf(A[a].x - B[b].x), W.x, s);  // abs folds into VOP3 src mod
        s = fmaf(fabsf(A[a].y - B[b].y), W.y, s);
        s = fmaf(fabsf(A[a].z - B[b].z), W.z, s);
        s = fmaf(fabsf(A[a].w - B[b].w), W.w, s);
        acc[a][b] = s;
      }
    }
  }

  const float bv = bias[0];
  #pragma unroll
  for (int a = 0; a < 4; ++a) {
    const int row = bi + ty + 16 * a;
    #pragma unroll
    for (int b = 0; b < 4; ++b) {
      const int col = bj + tx + 16 * b;
      S[row * N + col] = fmaxf(acc[a][b] + bv, 0.f);
    }
  }
}

// ---------------------------------------------------------------------------
// Phase B: in-place row softmax. One block (256 threads) per row; each thread
// owns one float4 (4 contiguous cols). Wave-64 shuffle reduce + tiny LDS.
// ---------------------------------------------------------------------------
__global__ __launch_bounds__(256) void softmax_kernel(float* __restrict__ S) {
  __shared__ float sred[8];
  const int t = threadIdx.x;
  float4* rowp = reinterpret_cast<float4*>(S + blockIdx.x * N);
  float4 v = rowp[t];

  // --- row max ---
  float m = fmaxf(fmaxf(v.x, v.y), fmaxf(v.z, v.w));
  #pragma unroll
  for (int o = 32; o > 0; o >>= 1) m = fmaxf(m, __shfl_xor(m, o, 64));
  if ((t & 63) == 0) sred[t >> 6] = m;
  __syncthreads();
  m = fmaxf(fmaxf(sred[0], sred[1]), fmaxf(sred[2], sred[3]));

  // --- exp + row sum ---
  float4 e;
  e.x = __expf(v.x - m);
  e.y = __expf(v.y - m);
  e.z = __expf(v.z - m);
  e.w = __expf(v.w - m);
  float s = (e.x + e.y) + (e.z + e.w);
  #pragma unroll
  for (int o = 32; o > 0; o >>= 1) s += __shfl_xor(s, o, 64);
  if ((t & 63) == 0) sred[4 + (t >> 6)] = s;
  __syncthreads();
  s = (sred[4] + sred[5]) + (sred[6] + sred[7]);

  const float r = 1.0f / s;
  e.x *= r; e.y *= r; e.z *= r; e.w *= r;
  rowp[t] = e;
}

extern "C" void kernel_launch(void* const* d_in, const int* in_sizes, int n_in,
                              void* d_out, int out_size, void* d_ws, size_t ws_size,
                              hipStream_t stream) {
  const float* x  = (const float*)d_in[0];
  const float* w  = (const float*)d_in[1];
  const float* b  = (const float*)d_in[2];
  float* out = (float*)d_out;

  dim3 grid(N / 64, N / 64);                 // 16x16 = 256 blocks
  scores_kernel<<<grid, 256, 0, stream>>>(x, w, b, out);
  softmax_kernel<<<N, 256, 0, stream>>>(out);
}

// Round 2
// 74.062 us; speedup vs baseline: 1.0113x; 1.0113x over previous
//
#include <hip/hip_runtime.h>

#define N 1024
#define D 128
#define PAD 132   // 128+4: rows 16B-aligned (528 B), bank stride 132%32=4

// ---------------------------------------------------------------------------
// Phase A: S[i][j] = relu( sum_d |x[i][d]-x[j][d]| * w[d] + bias )
// Tile 64 rows x 32 cols per block, 256 threads, micro-tile 4x2.
// grid = (N/32, N/64) = 512 blocks -> 2 blocks/CU -> 2 waves/SIMD.
// w is read as wave-uniform scalar loads (SGPR operands), not LDS.
// ---------------------------------------------------------------------------
__global__ __launch_bounds__(256) void scores_kernel(
    const float* __restrict__ x, const float* __restrict__ w,
    const float* __restrict__ bias, float* __restrict__ S) {
  __shared__ float sxi[64 * PAD];
  __shared__ float sxj[32 * PAD];

  const int t  = threadIdx.x;
  const int bi = blockIdx.y * 64;   // row base
  const int bj = blockIdx.x * 32;   // col base

  // ---- stage tiles: coalesced float4 global reads, one barrier ----
  {
    const int c  = t & 31;   // float4 index within a 128-float row
    const int r0 = t >> 5;   // 0..7
    #pragma unroll
    for (int p = 0; p < 8; ++p) {   // 64 rows of xi
      const int r = r0 + p * 8;
      const float4 v = reinterpret_cast<const float4*>(x)[(bi + r) * 32 + c];
      *reinterpret_cast<float4*>(&sxi[r * PAD + c * 4]) = v;
    }
    #pragma unroll
    for (int p = 0; p < 4; ++p) {   // 32 rows of xj
      const int r = r0 + p * 8;
      const float4 v = reinterpret_cast<const float4*>(x)[(bj + r) * 32 + c];
      *reinterpret_cast<float4*>(&sxj[r * PAD + c * 4]) = v;
    }
  }
  __syncthreads();

  const int tx = t & 15;   // col group: cols tx + 16*b, b=0..1
  const int ty = t >> 4;   // row group: rows ty + 16*a, a=0..3

  float acc[4][2];
  #pragma unroll
  for (int a = 0; a < 4; ++a)
    #pragma unroll
    for (int b = 0; b < 2; ++b) acc[a][b] = 0.f;

  #pragma unroll 4
  for (int d = 0; d < D; d += 4) {
    // wave-uniform -> s_load, hoisted out by the compiler
    const float4 W = reinterpret_cast<const float4*>(w)[d >> 2];
    float4 A[4], B[2];
    #pragma unroll
    for (int a = 0; a < 4; ++a)   // 4 addrs/wave, 16-lane broadcast
      A[a] = *reinterpret_cast<const float4*>(&sxi[(ty + 16 * a) * PAD + d]);
    #pragma unroll
    for (int b = 0; b < 2; ++b)   // 16 addrs/wave, 2-way alias (free)
      B[b] = *reinterpret_cast<const float4*>(&sxj[(tx + 16 * b) * PAD + d]);

    #pragma unroll
    for (int a = 0; a < 4; ++a) {
      #pragma unroll
      for (int b = 0; b < 2; ++b) {
        float s = acc[a][b];
        s = fmaf(fabsf(A[a].x - B[b].x), W.x, s);
        s = fmaf(fabsf(A[a].y - B[b].y), W.y, s);
        s = fmaf(fabsf(A[a].z - B[b].z), W.z, s);
        s = fmaf(fabsf(A[a].w - B[b].w), W.w, s);
        acc[a][b] = s;
      }
    }
  }

  const float bv = bias[0];
  #pragma unroll
  for (int a = 0; a < 4; ++a) {
    const int row = bi + ty + 16 * a;
    #pragma unroll
    for (int b = 0; b < 2; ++b) {
      const int col = bj + tx + 16 * b;
      S[row * N + col] = fmaxf(acc[a][b] + bv, 0.f);
    }
  }
}

// ---------------------------------------------------------------------------
// Phase B: in-place row softmax. One block (256 threads) per row.
// ---------------------------------------------------------------------------
__global__ __launch_bounds__(256) void softmax_kernel(float* __restrict__ S) {
  __shared__ float sred[8];
  const int t = threadIdx.x;
  float4* rowp = reinterpret_cast<float4*>(S + blockIdx.x * N);
  float4 v = rowp[t];

  float m = fmaxf(fmaxf(v.x, v.y), fmaxf(v.z, v.w));
  #pragma unroll
  for (int o = 32; o > 0; o >>= 1) m = fmaxf(m, __shfl_xor(m, o, 64));
  if ((t & 63) == 0) sred[t >> 6] = m;
  __syncthreads();
  m = fmaxf(fmaxf(sred[0], sred[1]), fmaxf(sred[2], sred[3]));

  float4 e;
  e.x = __expf(v.x - m);
  e.y = __expf(v.y - m);
  e.z = __expf(v.z - m);
  e.w = __expf(v.w - m);
  float s = (e.x + e.y) + (e.z + e.w);
  #pragma unroll
  for (int o = 32; o > 0; o >>= 1) s += __shfl_xor(s, o, 64);
  if ((t & 63) == 0) sred[4 + (t >> 6)] = s;
  __syncthreads();
  s = (sred[4] + sred[5]) + (sred[6] + sred[7]);

  const float r = 1.0f / s;
  e.x *= r; e.y *= r; e.z *= r; e.w *= r;
  rowp[t] = e;
}

extern "C" void kernel_launch(void* const* d_in, const int* in_sizes, int n_in,
                              void* d_out, int out_size, void* d_ws, size_t ws_size,
                              hipStream_t stream) {
  const float* x  = (const float*)d_in[0];
  const float* w  = (const float*)d_in[1];
  const float* b  = (const float*)d_in[2];
  float* out = (float*)d_out;

  dim3 grid(N / 32, N / 64);                 // 32x16 = 512 blocks, 2/CU
  scores_kernel<<<grid, 256, 0, stream>>>(x, w, b, out);
  softmax_kernel<<<N, 256, 0, stream>>>(out);
}